// Round 5
// baseline (702.024 us; speedup 1.0000x reference)
//
#include <hip/hip_runtime.h>

// ---------------------------------------------------------------------------
// QGroupLinear: y[m,n] = sum_k x[m,k] * (qw[n,k] * sw[n, k/G]) + bias[n]
// M=4096 (B*S), K=4096, N=11008, G=128.
// R8: keep R7's proven two-barrier BK=64 loop; ONE change: wave tiling.
//     BM 128->256, per-wave output 64x64 -> 128x64 (acc[8][4], 8-phase
//     template's per-wave geometry). Effects: 2x MFMA per barrier event
//     (64/wave/iter), LDS-read-per-MFMA 0.5 -> 0.375 b128 (af[8]+bf[4]
//     feed 32 MFMA). LDS 48 KB (A 256x64 + B 128x64), ~224 unified regs
//     -> 2 blocks/CU. R7 measured: BK32->64 gave 432->341 us (MfmaUtil
//     36->52) by halving drain events; this halves them again per output.
// Measured & rejected: BK=128 single-buf (m132: 874->508 TF, occupancy
//     cliff); R4/R5 8-phase ports (432/568); R6 2-phase dbuf (455).
//     i8-MFMA (group-fixup VALU-bound), MX-fp8 (error vs 2.0 budget).
// R5 carry: split branch-free preps. R7 carry: BK=64 row-XOR swizzle
//     (conflicts 0), XCD-aware block swizzle.
// ---------------------------------------------------------------------------

typedef __attribute__((ext_vector_type(8))) short short8;
typedef __attribute__((ext_vector_type(4))) float floatx4;

__device__ __forceinline__ unsigned short f2bf_rne(float f) {
  union { float f; unsigned int u; } c;
  c.f = f;
  unsigned int u = c.u;
  u += 0x7FFFu + ((u >> 16) & 1u);   // round-to-nearest-even
  return (unsigned short)(u >> 16);
}

// ---- prep A: xb = bf16(x), 8 elems per chunk, grid-stride ----------------
__global__ void prep_x_kernel(const float* __restrict__ x,
                              short* __restrict__ xb, long nchunks) {
  long stride = (long)gridDim.x * blockDim.x;
  for (long c = (long)blockIdx.x * blockDim.x + threadIdx.x;
       c < nchunks; c += stride) {
    const float4* p = (const float4*)(x + c * 8);
    float4 a = p[0], b = p[1];
    short8 o;
    o[0] = (short)f2bf_rne(a.x); o[1] = (short)f2bf_rne(a.y);
    o[2] = (short)f2bf_rne(a.z); o[3] = (short)f2bf_rne(a.w);
    o[4] = (short)f2bf_rne(b.x); o[5] = (short)f2bf_rne(b.y);
    o[6] = (short)f2bf_rne(b.z); o[7] = (short)f2bf_rne(b.w);
    *(short8*)(xb + c * 8) = o;
  }
}

// ---- prep B: wb = bf16(qw * sw), 8 elems per chunk, grid-stride ----------
__global__ void prep_w_kernel(const int* __restrict__ qw,
                              const float* __restrict__ sw,
                              short* __restrict__ wb, long nchunks,
                              int kc, int kcshift, int gc, int gcshift,
                              int ngroups) {
  long stride = (long)gridDim.x * blockDim.x;
  for (long c = (long)blockIdx.x * blockDim.x + threadIdx.x;
       c < nchunks; c += stride) {
    int n, kch;
    if (kcshift >= 0) {
      n = (int)(c >> kcshift);
      kch = (int)(c & (long)(kc - 1));
    } else {
      n = (int)(c / kc);
      kch = (int)(c - (long)n * kc);
    }
    int g = (gcshift >= 0) ? (kch >> gcshift) : (kch / gc);
    float s = sw[(long)n * ngroups + g];
    const int* q = qw + c * 8;
    int4 q0 = *(const int4*)q;
    int4 q1 = *(const int4*)(q + 4);
    short8 o;
    o[0] = (short)f2bf_rne((float)q0.x * s);
    o[1] = (short)f2bf_rne((float)q0.y * s);
    o[2] = (short)f2bf_rne((float)q0.z * s);
    o[3] = (short)f2bf_rne((float)q0.w * s);
    o[4] = (short)f2bf_rne((float)q1.x * s);
    o[5] = (short)f2bf_rne((float)q1.y * s);
    o[6] = (short)f2bf_rne((float)q1.z * s);
    o[7] = (short)f2bf_rne((float)q1.w * s);
    *(short8*)(wb + c * 8) = o;
  }
}

// ---- bf16 MFMA GEMM: Y[M][N] = Xb[M][K] * Wb[N][K]^T + bias ---------------
#define BM 256
#define BN 128
#define BK 64

__global__ __launch_bounds__(256, 2) void gemm_bt_kernel(
    const short* __restrict__ Xb,    // [M][K] bf16 bits
    const short* __restrict__ Wb,    // [N][K] bf16 bits
    const float* __restrict__ bias,  // [N]
    float* __restrict__ Y,           // [M][N]
    int M, int N, int K) {
  __shared__ short As[BM * BK];  // 32 KB
  __shared__ short Bs[BN * BK];  // 16 KB

  const int t = threadIdx.x;     // 0..255
  const int wave = t >> 6;       // 0..3
  const int lane = t & 63;
  const int wm = wave >> 1;      // 0..1 (M 128-half of the 256-row A tile)
  const int wn = wave & 1;       // 0..1 (N 64-half of the 128-row B tile)
  const int quad = lane >> 4;    // 0..3
  const int l16 = lane & 15;

  // ---- XCD-aware swizzle: xcd = bid%8 owns M-tile stripe, sweeps N;
  // consecutive same-XCD blocks share one B panel in that XCD's L2.
  const int gn = gridDim.x, gm = gridDim.y;
  int mt, nt;
  if ((gm & 7) == 0) {
    int stripe = gm >> 3;
    int bid = blockIdx.y * gn + blockIdx.x;
    int xcd = bid & 7;
    int q = bid >> 3;
    int msub = q % stripe;
    nt = q / stripe;
    mt = xcd * stripe + msub;
  } else {
    mt = blockIdx.y; nt = blockIdx.x;
  }
  const int tileM = mt * BM;
  const int tileN = nt * BN;

  floatx4 acc[8][4];
#pragma unroll
  for (int i = 0; i < 8; i++)
#pragma unroll
    for (int j = 0; j < 4; j++) acc[i][j] = {0.f, 0.f, 0.f, 0.f};

  const short* Ag = Xb + (long)tileM * K;
  const short* Bg = Wb + (long)tileN * K;

  // fragment read: row r, global chunk g -> physical chunk g ^ (r&7);
  // frag rows are i*16+l16 -> XOR (l16&7). K-slice s: chunk base s*4+quad.
  const int c0 = (quad ^ (l16 & 7)) << 3;    // shorts

  for (int k0 = 0; k0 < K; k0 += BK) {
    // stage A: 2048 16B-chunks; thread t fills physical chunks jj*256+t.
    // physical (r = c>>3, pc = c&7) holds global chunk pc ^ (r&7)
    // (same 128B row segment -> coalescing unchanged).
#pragma unroll
    for (int jj = 0; jj < 8; ++jj) {
      const int c = (jj << 8) | t;
      const int r = c >> 3;
      const int g = (c & 7) ^ (r & 7);
      __builtin_amdgcn_global_load_lds(
          (const __attribute__((address_space(1))) void*)(
              Ag + (long)r * K + k0 + (g << 3)),
          (__attribute__((address_space(3))) void*)(As + (c << 3)),
          16, 0, 0);
    }
    // stage B: 1024 chunks
#pragma unroll
    for (int jj = 0; jj < 4; ++jj) {
      const int c = (jj << 8) | t;
      const int r = c >> 3;
      const int g = (c & 7) ^ (r & 7);
      __builtin_amdgcn_global_load_lds(
          (const __attribute__((address_space(1))) void*)(
              Bg + (long)r * K + k0 + (g << 3)),
          (__attribute__((address_space(3))) void*)(Bs + (c << 3)),
          16, 0, 0);
    }
    __syncthreads();   // drains vmcnt: tile resident

    const short* Aw = As + wm * 128 * BK;
    const short* Bw = Bs + wn * 64 * BK;
#pragma unroll
    for (int s = 0; s < 2; ++s) {
      const int cs = c0 ^ (s << 5);
      short8 af[8], bf[4];
#pragma unroll
      for (int i = 0; i < 8; i++)
        af[i] = *(const short8*)(Aw + (i * 16 + l16) * BK + cs);
#pragma unroll
      for (int j = 0; j < 4; j++)
        bf[j] = *(const short8*)(Bw + (j * 16 + l16) * BK + cs);
#pragma unroll
      for (int i = 0; i < 8; i++)
#pragma unroll
        for (int j = 0; j < 4; j++)
          acc[i][j] = __builtin_amdgcn_mfma_f32_16x16x32_bf16(
              af[i], bf[j], acc[i][j], 0, 0, 0);
    }
    __syncthreads();   // protect LDS before next stage (single buffer)
  }

  // epilogue: C/D layout col=lane&15 (n), row=quad*4+reg (m)
  const int mbase = tileM + wm * 128;
  const int nbase = tileN + wn * 64;
#pragma unroll
  for (int j = 0; j < 4; j++) {
    int n = nbase + j * 16 + l16;
    float bv = bias[n];
#pragma unroll
    for (int i = 0; i < 8; i++) {
#pragma unroll
      for (int r = 0; r < 4; r++) {
        int m = mbase + i * 16 + quad * 4 + r;
        Y[(long)m * N + n] = acc[i][j][r] + bv;
      }
    }
  }
}

// ---- fallback (only if ws too small / odd shapes): correct but slow -------
__global__ void naive_kernel(const float* __restrict__ x,
                             const int* __restrict__ qw,
                             const float* __restrict__ sw,
                             const float* __restrict__ bias,
                             float* __restrict__ y,
                             int M, int N, int K, int G) {
  long idx = (long)blockIdx.x * blockDim.x + threadIdx.x;
  if (idx >= (long)M * N) return;
  int m = (int)(idx / N), n = (int)(idx % N);
  int ng = K / G;
  float acc = 0.f;
  for (int g = 0; g < ng; g++) {
    float s = sw[(long)n * ng + g];
    float part = 0.f;
    for (int k = g * G; k < (g + 1) * G; k++)
      part += x[(long)m * K + k] * (float)qw[(long)n * K + k];
    acc += part * s;
  }
  y[idx] = acc + bias[n];
}

extern "C" void kernel_launch(void* const* d_in, const int* in_sizes, int n_in,
                              void* d_out, int out_size, void* d_ws, size_t ws_size,
                              hipStream_t stream) {
  const float* x = (const float*)d_in[0];
  const int* qw = (const int*)d_in[1];
  const float* sw = (const float*)d_in[2];
  const float* bias = (const float*)d_in[3];
  float* y = (float*)d_out;

  const int N = in_sizes[3];
  const int K = in_sizes[1] / N;
  const int M = in_sizes[0] / K;
  const int ngroups = in_sizes[2] / N;
  const int G = K / ngroups;

  const long MK = (long)M * K;
  const long NK = (long)N * K;
  const size_t need = (size_t)(MK + NK) * sizeof(short);

  if (ws_size < need || (M % BM) || (N % BN) || (K % BK) || (G % 8)) {
    long total = (long)M * N;
    naive_kernel<<<(unsigned)((total + 255) / 256), 256, 0, stream>>>(
        x, qw, sw, bias, y, M, N, K, G);
    return;
  }

  short* xb = (short*)d_ws;
  short* wb = xb + MK;

  const int kc = K / 8;        // chunks per row
  const int gc = G / 8;        // chunks per group
  int kcshift = ((kc & (kc - 1)) == 0) ? __builtin_ctz((unsigned)kc) : -1;
  int gcshift = ((gc & (gc - 1)) == 0) ? __builtin_ctz((unsigned)gc) : -1;

  prep_x_kernel<<<2048, 256, 0, stream>>>(x, xb, MK / 8);
  prep_w_kernel<<<2048, 256, 0, stream>>>(qw, sw, wb, NK / 8,
                                          kc, kcshift, gc, gcshift, ngroups);

  dim3 grid((unsigned)(N / BN), (unsigned)(M / BM));
  gemm_bt_kernel<<<grid, 256, 0, stream>>>(xb, wb, bias, y, M, N, K);
}

// Round 7
// 660.023 us; speedup vs baseline: 1.0636x; 1.0636x over previous
//
#include <hip/hip_runtime.h>

// ---------------------------------------------------------------------------
// QGroupLinear: y[m,n] = sum_k x[m,k] * (qw[n,k] * sw[n, k/G]) + bias[n]
// M=4096 (B*S), K=4096, N=11008, G=128.
// R9b: R9 with the compile fix: __builtin_nontemporal_load requires clang
//     ext_vector types, not HIP_vector_type float4/int4.
//     GEMM = byte-identical R7 (best measured: 341 us, MfmaUtil 52%,
//     4 blocks/CU; BK=64 two-barrier single-buffer, row-XOR swizzle,
//     XCD-aware block swizzle). R8 taught: cross-block TLP (4 blocks/CU)
//     is what hides the barrier drain; occupancy-halving variants lose.
//     Prep pass: ONE merged kernel, 16 elems/thread (64B nontemporal
//     loads, 2x short8 stores), one sw load per 16 weights. Purpose:
//     bound the persistent ~300 us (total - gemm) gap.
// Measured map (gemm dur): BK32 432 | BK64 341 (R7, best) | 8-phase ports
//     432/568 | 2-phase dbuf 455 | 256x128 tile 382. Rejected on paper:
//     i8-MFMA (group-fixup VALU-bound), MX-fp8 (error vs budget),
//     BK=128 (m132 occupancy cliff).
// ---------------------------------------------------------------------------

typedef __attribute__((ext_vector_type(8))) short short8;
typedef __attribute__((ext_vector_type(4))) float floatx4;
typedef __attribute__((ext_vector_type(4))) float f32x4v;
typedef __attribute__((ext_vector_type(4))) int i32x4v;

__device__ __forceinline__ unsigned short f2bf_rne(float f) {
  union { float f; unsigned int u; } c;
  c.f = f;
  unsigned int u = c.u;
  u += 0x7FFFu + ((u >> 16) & 1u);   // round-to-nearest-even
  return (unsigned short)(u >> 16);
}

// ---- merged prep: xb = bf16(x); wb = bf16(qw * sw). 16 elems/thread. -----
// chunk c in [0, nx16): x-convert; c in [nx16, total16): w-dequant.
// Requires K%16==0 and G%16==0 (launcher-checked) so one 16-elem run is
// inside one row and one quant group.
__global__ void prep_kernel(const float* __restrict__ x,
                            const int* __restrict__ qw,
                            const float* __restrict__ sw,
                            short* __restrict__ xb,
                            short* __restrict__ wb,
                            long nx16, long total16,
                            int kp, int kpshift, int gp, int gpshift,
                            int ngroups) {
  long stride = (long)gridDim.x * blockDim.x;
  for (long c = (long)blockIdx.x * blockDim.x + threadIdx.x;
       c < total16; c += stride) {
    if (c < nx16) {
      const f32x4v* p = (const f32x4v*)(x + c * 16);
      f32x4v a = __builtin_nontemporal_load(p + 0);
      f32x4v b = __builtin_nontemporal_load(p + 1);
      f32x4v d = __builtin_nontemporal_load(p + 2);
      f32x4v e = __builtin_nontemporal_load(p + 3);
      short8 o0, o1;
      o0[0] = (short)f2bf_rne(a[0]); o0[1] = (short)f2bf_rne(a[1]);
      o0[2] = (short)f2bf_rne(a[2]); o0[3] = (short)f2bf_rne(a[3]);
      o0[4] = (short)f2bf_rne(b[0]); o0[5] = (short)f2bf_rne(b[1]);
      o0[6] = (short)f2bf_rne(b[2]); o0[7] = (short)f2bf_rne(b[3]);
      o1[0] = (short)f2bf_rne(d[0]); o1[1] = (short)f2bf_rne(d[1]);
      o1[2] = (short)f2bf_rne(d[2]); o1[3] = (short)f2bf_rne(d[3]);
      o1[4] = (short)f2bf_rne(e[0]); o1[5] = (short)f2bf_rne(e[1]);
      o1[6] = (short)f2bf_rne(e[2]); o1[7] = (short)f2bf_rne(e[3]);
      short8* ob = (short8*)(xb + c * 16);
      ob[0] = o0; ob[1] = o1;
    } else {
      long p = c - nx16;               // 16-elem index into [N][K/16]
      int n, kpi;
      if (kpshift >= 0) {
        n = (int)(p >> kpshift);
        kpi = (int)(p & (long)(kp - 1));
      } else {
        n = (int)(p / kp);
        kpi = (int)(p - (long)n * kp);
      }
      int g = (gpshift >= 0) ? (kpi >> gpshift) : (kpi / gp);
      float s = sw[(long)n * ngroups + g];
      const i32x4v* q = (const i32x4v*)(qw + p * 16);
      i32x4v q0 = __builtin_nontemporal_load(q + 0);
      i32x4v q1 = __builtin_nontemporal_load(q + 1);
      i32x4v q2 = __builtin_nontemporal_load(q + 2);
      i32x4v q3 = __builtin_nontemporal_load(q + 3);
      short8 o0, o1;
      o0[0] = (short)f2bf_rne((float)q0[0] * s);
      o0[1] = (short)f2bf_rne((float)q0[1] * s);
      o0[2] = (short)f2bf_rne((float)q0[2] * s);
      o0[3] = (short)f2bf_rne((float)q0[3] * s);
      o0[4] = (short)f2bf_rne((float)q1[0] * s);
      o0[5] = (short)f2bf_rne((float)q1[1] * s);
      o0[6] = (short)f2bf_rne((float)q1[2] * s);
      o0[7] = (short)f2bf_rne((float)q1[3] * s);
      o1[0] = (short)f2bf_rne((float)q2[0] * s);
      o1[1] = (short)f2bf_rne((float)q2[1] * s);
      o1[2] = (short)f2bf_rne((float)q2[2] * s);
      o1[3] = (short)f2bf_rne((float)q2[3] * s);
      o1[4] = (short)f2bf_rne((float)q3[0] * s);
      o1[5] = (short)f2bf_rne((float)q3[1] * s);
      o1[6] = (short)f2bf_rne((float)q3[2] * s);
      o1[7] = (short)f2bf_rne((float)q3[3] * s);
      short8* ob = (short8*)(wb + p * 16);
      ob[0] = o0; ob[1] = o1;
    }
  }
}

// ---- bf16 MFMA GEMM: Y[M][N] = Xb[M][K] * Wb[N][K]^T + bias ---------------
// Byte-identical to R7 (measured 341 us / MfmaUtil 52% / 0 conflicts).
#define BM 128
#define BN 128
#define BK 64

__global__ __launch_bounds__(256, 4) void gemm_bt_kernel(
    const short* __restrict__ Xb,    // [M][K] bf16 bits
    const short* __restrict__ Wb,    // [N][K] bf16 bits
    const float* __restrict__ bias,  // [N]
    float* __restrict__ Y,           // [M][N]
    int M, int N, int K) {
  __shared__ short As[BM * BK];  // 16 KB
  __shared__ short Bs[BN * BK];  // 16 KB

  const int t = threadIdx.x;     // 0..255
  const int wave = t >> 6;       // 0..3
  const int lane = t & 63;
  const int wm = wave >> 1;      // 0..1 (m-half)
  const int wn = wave & 1;       // 0..1 (n-half)
  const int quad = lane >> 4;    // 0..3
  const int l16 = lane & 15;

  // ---- XCD-aware swizzle: xcd = bid%8 owns M-tile stripe, sweeps N;
  // consecutive same-XCD blocks share one B panel in that XCD's L2.
  const int gn = gridDim.x, gm = gridDim.y;
  int mt, nt;
  if ((gm & 7) == 0) {
    int stripe = gm >> 3;
    int bid = blockIdx.y * gn + blockIdx.x;
    int xcd = bid & 7;
    int q = bid >> 3;
    int msub = q % stripe;
    nt = q / stripe;
    mt = xcd * stripe + msub;
  } else {
    mt = blockIdx.y; nt = blockIdx.x;
  }
  const int tileM = mt * BM;
  const int tileN = nt * BN;

  floatx4 acc[4][4];
#pragma unroll
  for (int i = 0; i < 4; i++)
#pragma unroll
    for (int j = 0; j < 4; j++) acc[i][j] = {0.f, 0.f, 0.f, 0.f};

  const short* Ag = Xb + (long)tileM * K;
  const short* Bg = Wb + (long)tileN * K;

  // fragment read: row r = (half)*64 + i*16 + l16, global chunk g = s*4+quad
  // -> physical chunk g ^ (r&7) = g ^ (l16&7). ks1 offset = c0 ^ 32 shorts.
  const int c0 = (quad ^ (l16 & 7)) << 3;    // shorts

  for (int k0 = 0; k0 < K; k0 += BK) {
    // stage: thread t fills physical chunks {t, 256+t, 512+t, 768+t} of each
    // operand; physical (r = c>>3, pc = c&7) holds global chunk pc ^ (r&7).
#pragma unroll
    for (int jj = 0; jj < 4; ++jj) {
      const int c = (jj << 8) | t;
      const int r = c >> 3;
      const int g = (c & 7) ^ (r & 7);
      __builtin_amdgcn_global_load_lds(
          (const __attribute__((address_space(1))) void*)(
              Ag + (long)r * K + k0 + (g << 3)),
          (__attribute__((address_space(3))) void*)(As + (c << 3)),
          16, 0, 0);
    }
#pragma unroll
    for (int jj = 0; jj < 4; ++jj) {
      const int c = (jj << 8) | t;
      const int r = c >> 3;
      const int g = (c & 7) ^ (r & 7);
      __builtin_amdgcn_global_load_lds(
          (const __attribute__((address_space(1))) void*)(
              Bg + (long)r * K + k0 + (g << 3)),
          (__attribute__((address_space(3))) void*)(Bs + (c << 3)),
          16, 0, 0);
    }
    __syncthreads();   // drains vmcnt: tile resident

    const short* Aw = As + wm * 64 * BK;
    const short* Bw = Bs + wn * 64 * BK;
#pragma unroll
    for (int s = 0; s < 2; ++s) {
      const int cs = c0 ^ (s << 5);
      short8 af[4], bf[4];
#pragma unroll
      for (int i = 0; i < 4; i++)
        af[i] = *(const short8*)(Aw + (i * 16 + l16) * BK + cs);
#pragma unroll
      for (int j = 0; j < 4; j++)
        bf[j] = *(const short8*)(Bw + (j * 16 + l16) * BK + cs);
#pragma unroll
      for (int i = 0; i < 4; i++)
#pragma unroll
        for (int j = 0; j < 4; j++)
          acc[i][j] = __builtin_amdgcn_mfma_f32_16x16x32_bf16(
              af[i], bf[j], acc[i][j], 0, 0, 0);
    }
    __syncthreads();   // protect LDS before next stage (single buffer)
  }

  // epilogue: C/D layout col=lane&15 (n), row=quad*4+reg (m)
  const int mbase = tileM + wm * 64;
  const int nbase = tileN + wn * 64;
#pragma unroll
  for (int i = 0; i < 4; i++) {
#pragma unroll
    for (int j = 0; j < 4; j++) {
      int n = nbase + j * 16 + l16;
      float bv = bias[n];
#pragma unroll
      for (int r = 0; r < 4; r++) {
        int m = mbase + i * 16 + quad * 4 + r;
        Y[(long)m * N + n] = acc[i][j][r] + bv;
      }
    }
  }
}

// ---- fallback (only if ws too small / odd shapes): correct but slow -------
__global__ void naive_kernel(const float* __restrict__ x,
                             const int* __restrict__ qw,
                             const float* __restrict__ sw,
                             const float* __restrict__ bias,
                             float* __restrict__ y,
                             int M, int N, int K, int G) {
  long idx = (long)blockIdx.x * blockDim.x + threadIdx.x;
  if (idx >= (long)M * N) return;
  int m = (int)(idx / N), n = (int)(idx % N);
  int ng = K / G;
  float acc = 0.f;
  for (int g = 0; g < ng; g++) {
    float s = sw[(long)n * ng + g];
    float part = 0.f;
    for (int k = g * G; k < (g + 1) * G; k++)
      part += x[(long)m * K + k] * (float)qw[(long)n * K + k];
    acc += part * s;
  }
  y[idx] = acc + bias[n];
}

extern "C" void kernel_launch(void* const* d_in, const int* in_sizes, int n_in,
                              void* d_out, int out_size, void* d_ws, size_t ws_size,
                              hipStream_t stream) {
  const float* x = (const float*)d_in[0];
  const int* qw = (const int*)d_in[1];
  const float* sw = (const float*)d_in[2];
  const float* bias = (const float*)d_in[3];
  float* y = (float*)d_out;

  const int N = in_sizes[3];
  const int K = in_sizes[1] / N;
  const int M = in_sizes[0] / K;
  const int ngroups = in_sizes[2] / N;
  const int G = K / ngroups;

  const long MK = (long)M * K;
  const long NK = (long)N * K;
  const size_t need = (size_t)(MK + NK) * sizeof(short);

  if (ws_size < need || (M % BM) || (N % BN) || (K % BK) || (G % 16) ||
      (K % 16)) {
    long total = (long)M * N;
    naive_kernel<<<(unsigned)((total + 255) / 256), 256, 0, stream>>>(
        x, qw, sw, bias, y, M, N, K, G);
    return;
  }

  short* xb = (short*)d_ws;
  short* wb = xb + MK;

  const int kp = K / 16;       // 16-elem runs per row
  const int gp = G / 16;       // 16-elem runs per group
  int kpshift = ((kp & (kp - 1)) == 0) ? __builtin_ctz((unsigned)kp) : -1;
  int gpshift = ((gp & (gp - 1)) == 0) ? __builtin_ctz((unsigned)gp) : -1;

  long nx16 = MK / 16;
  long total16 = nx16 + NK / 16;
  prep_kernel<<<2048, 256, 0, stream>>>(x, qw, sw, xb, wb, nx16, total16,
                                        kp, kpshift, gp, gpshift, ngroups);

  dim3 grid((unsigned)(N / BN), (unsigned)(M / BM));
  gemm_bt_kernel<<<grid, 256, 0, stream>>>(xb, wb, bias, y, M, N, K);
}

// Round 8
// 632.014 us; speedup vs baseline: 1.1108x; 1.0443x over previous
//
#include <hip/hip_runtime.h>

// ---------------------------------------------------------------------------
// QGroupLinear: y[m,n] = sum_k x[m,k] * (qw[n,k] * sw[n, k/G]) + bias[n]
// M=4096 (B*S), K=4096, N=11008, G=128.
// R10: (1) prep rebuilt LANE-CONTIGUOUS: 4 elems/thread/iter = one 16B
//     load per lane at lane-stride 16B (the m13 6.3TB/s pattern), 8B
//     short4 store. All prior preps (8/16 elems/thread) had lane-stride
//     32/64B -> scattered 16B gathers -> ~1.2 TB/s, ~330 us. Predicted
//     prep ~70-90 us.
//     (2) GEMM: nontemporal Y stores. FETCH 508 MB vs 123 MB working set
//     (fits L3): the 176 MB Y write-stream evicts xb/wb from L3 ->
//     HBM re-fetch + longer staging latency at the barrier drain.
//     GEMM otherwise byte-identical R7 (330-341 us, MfmaUtil 52-54%).
// Measured map (gemm dur): BK32 432 | BK64 341/330 (best) | 8-phase ports
//     432/568 | 2-phase dbuf 455 | 256x128 tile 382 (occupancy cliff).
// ---------------------------------------------------------------------------

typedef __attribute__((ext_vector_type(8))) short short8;
typedef __attribute__((ext_vector_type(4))) short short4v;
typedef __attribute__((ext_vector_type(4))) float floatx4;
typedef __attribute__((ext_vector_type(4))) float f32x4v;
typedef __attribute__((ext_vector_type(4))) int i32x4v;

__device__ __forceinline__ unsigned short f2bf_rne(float f) {
  union { float f; unsigned int u; } c;
  c.f = f;
  unsigned int u = c.u;
  u += 0x7FFFu + ((u >> 16) & 1u);   // round-to-nearest-even
  return (unsigned short)(u >> 16);
}

// ---- merged prep, lane-contiguous: 4 elems/thread/iteration ---------------
// chunk c in [0, nx4): xb[c*4..] = bf16(x[c*4..]); c in [nx4, total4):
// wb = bf16(qw * sw). Requires K%4==0, G%4==0 (launcher-checked).
__global__ void prep_kernel(const float* __restrict__ x,
                            const int* __restrict__ qw,
                            const float* __restrict__ sw,
                            short* __restrict__ xb,
                            short* __restrict__ wb,
                            long nx4, long total4,
                            int kq, int kqshift, int gq, int gqshift,
                            int ngroups) {
  long stride = (long)gridDim.x * blockDim.x;
  for (long c = (long)blockIdx.x * blockDim.x + threadIdx.x;
       c < total4; c += stride) {
    if (c < nx4) {
      f32x4v a = __builtin_nontemporal_load((const f32x4v*)(x + c * 4));
      short4v o;
      o[0] = (short)f2bf_rne(a[0]); o[1] = (short)f2bf_rne(a[1]);
      o[2] = (short)f2bf_rne(a[2]); o[3] = (short)f2bf_rne(a[3]);
      *(short4v*)(xb + c * 4) = o;
    } else {
      long p = c - nx4;               // 4-elem run index into [N][K/4]
      int n, kpi;
      if (kqshift >= 0) {
        n = (int)(p >> kqshift);
        kpi = (int)(p & (long)(kq - 1));
      } else {
        n = (int)(p / kq);
        kpi = (int)(p - (long)n * kq);
      }
      int g = (gqshift >= 0) ? (kpi >> gqshift) : (kpi / gq);
      float s = sw[(long)n * ngroups + g];
      i32x4v q = __builtin_nontemporal_load((const i32x4v*)(qw + p * 4));
      short4v o;
      o[0] = (short)f2bf_rne((float)q[0] * s);
      o[1] = (short)f2bf_rne((float)q[1] * s);
      o[2] = (short)f2bf_rne((float)q[2] * s);
      o[3] = (short)f2bf_rne((float)q[3] * s);
      *(short4v*)(wb + p * 4) = o;
    }
  }
}

// ---- bf16 MFMA GEMM: Y[M][N] = Xb[M][K] * Wb[N][K]^T + bias ---------------
// R7 structure (measured 330-341 us / MfmaUtil 52-54% / 0 conflicts);
// only change: nontemporal Y stores in the epilogue.
#define BM 128
#define BN 128
#define BK 64

__global__ __launch_bounds__(256, 4) void gemm_bt_kernel(
    const short* __restrict__ Xb,    // [M][K] bf16 bits
    const short* __restrict__ Wb,    // [N][K] bf16 bits
    const float* __restrict__ bias,  // [N]
    float* __restrict__ Y,           // [M][N]
    int M, int N, int K) {
  __shared__ short As[BM * BK];  // 16 KB
  __shared__ short Bs[BN * BK];  // 16 KB

  const int t = threadIdx.x;     // 0..255
  const int wave = t >> 6;       // 0..3
  const int lane = t & 63;
  const int wm = wave >> 1;      // 0..1 (m-half)
  const int wn = wave & 1;       // 0..1 (n-half)
  const int quad = lane >> 4;    // 0..3
  const int l16 = lane & 15;

  // ---- XCD-aware swizzle: xcd = bid%8 owns M-tile stripe, sweeps N;
  // all 8 XCDs work the same N-panel concurrently (L3 sharing), each
  // XCD's 4-tile A-stripe stays hot in its own L2.
  const int gn = gridDim.x, gm = gridDim.y;
  int mt, nt;
  if ((gm & 7) == 0) {
    int stripe = gm >> 3;
    int bid = blockIdx.y * gn + blockIdx.x;
    int xcd = bid & 7;
    int q = bid >> 3;
    int msub = q % stripe;
    nt = q / stripe;
    mt = xcd * stripe + msub;
  } else {
    mt = blockIdx.y; nt = blockIdx.x;
  }
  const int tileM = mt * BM;
  const int tileN = nt * BN;

  floatx4 acc[4][4];
#pragma unroll
  for (int i = 0; i < 4; i++)
#pragma unroll
    for (int j = 0; j < 4; j++) acc[i][j] = {0.f, 0.f, 0.f, 0.f};

  const short* Ag = Xb + (long)tileM * K;
  const short* Bg = Wb + (long)tileN * K;

  // fragment read: row r = (half)*64 + i*16 + l16, global chunk g = s*4+quad
  // -> physical chunk g ^ (r&7) = g ^ (l16&7). ks1 offset = c0 ^ 32 shorts.
  const int c0 = (quad ^ (l16 & 7)) << 3;    // shorts

  for (int k0 = 0; k0 < K; k0 += BK) {
    // stage: thread t fills physical chunks {t, 256+t, 512+t, 768+t} of each
    // operand; physical (r = c>>3, pc = c&7) holds global chunk pc ^ (r&7).
#pragma unroll
    for (int jj = 0; jj < 4; ++jj) {
      const int c = (jj << 8) | t;
      const int r = c >> 3;
      const int g = (c & 7) ^ (r & 7);
      __builtin_amdgcn_global_load_lds(
          (const __attribute__((address_space(1))) void*)(
              Ag + (long)r * K + k0 + (g << 3)),
          (__attribute__((address_space(3))) void*)(As + (c << 3)),
          16, 0, 0);
    }
#pragma unroll
    for (int jj = 0; jj < 4; ++jj) {
      const int c = (jj << 8) | t;
      const int r = c >> 3;
      const int g = (c & 7) ^ (r & 7);
      __builtin_amdgcn_global_load_lds(
          (const __attribute__((address_space(1))) void*)(
              Bg + (long)r * K + k0 + (g << 3)),
          (__attribute__((address_space(3))) void*)(Bs + (c << 3)),
          16, 0, 0);
    }
    __syncthreads();   // drains vmcnt: tile resident

    const short* Aw = As + wm * 64 * BK;
    const short* Bw = Bs + wn * 64 * BK;
#pragma unroll
    for (int s = 0; s < 2; ++s) {
      const int cs = c0 ^ (s << 5);
      short8 af[4], bf[4];
#pragma unroll
      for (int i = 0; i < 4; i++)
        af[i] = *(const short8*)(Aw + (i * 16 + l16) * BK + cs);
#pragma unroll
      for (int j = 0; j < 4; j++)
        bf[j] = *(const short8*)(Bw + (j * 16 + l16) * BK + cs);
#pragma unroll
      for (int i = 0; i < 4; i++)
#pragma unroll
        for (int j = 0; j < 4; j++)
          acc[i][j] = __builtin_amdgcn_mfma_f32_16x16x32_bf16(
              af[i], bf[j], acc[i][j], 0, 0, 0);
    }
    __syncthreads();   // protect LDS before next stage (single buffer)
  }

  // epilogue: C/D layout col=lane&15 (n), row=quad*4+reg (m).
  // Y stores nontemporal: never re-read; keep them out of L2/L3 so the
  // xb/wb working set (123 MB, L3-fit) stays resident.
  const int mbase = tileM + wm * 64;
  const int nbase = tileN + wn * 64;
#pragma unroll
  for (int i = 0; i < 4; i++) {
#pragma unroll
    for (int j = 0; j < 4; j++) {
      int n = nbase + j * 16 + l16;
      float bv = bias[n];
#pragma unroll
      for (int r = 0; r < 4; r++) {
        int m = mbase + i * 16 + quad * 4 + r;
        __builtin_nontemporal_store(acc[i][j][r] + bv, Y + (long)m * N + n);
      }
    }
  }
}

// ---- fallback (only if ws too small / odd shapes): correct but slow -------
__global__ void naive_kernel(const float* __restrict__ x,
                             const int* __restrict__ qw,
                             const float* __restrict__ sw,
                             const float* __restrict__ bias,
                             float* __restrict__ y,
                             int M, int N, int K, int G) {
  long idx = (long)blockIdx.x * blockDim.x + threadIdx.x;
  if (idx >= (long)M * N) return;
  int m = (int)(idx / N), n = (int)(idx % N);
  int ng = K / G;
  float acc = 0.f;
  for (int g = 0; g < ng; g++) {
    float s = sw[(long)n * ng + g];
    float part = 0.f;
    for (int k = g * G; k < (g + 1) * G; k++)
      part += x[(long)m * K + k] * (float)qw[(long)n * K + k];
    acc += part * s;
  }
  y[idx] = acc + bias[n];
}

extern "C" void kernel_launch(void* const* d_in, const int* in_sizes, int n_in,
                              void* d_out, int out_size, void* d_ws, size_t ws_size,
                              hipStream_t stream) {
  const float* x = (const float*)d_in[0];
  const int* qw = (const int*)d_in[1];
  const float* sw = (const float*)d_in[2];
  const float* bias = (const float*)d_in[3];
  float* y = (float*)d_out;

  const int N = in_sizes[3];
  const int K = in_sizes[1] / N;
  const int M = in_sizes[0] / K;
  const int ngroups = in_sizes[2] / N;
  const int G = K / ngroups;

  const long MK = (long)M * K;
  const long NK = (long)N * K;
  const size_t need = (size_t)(MK + NK) * sizeof(short);

  if (ws_size < need || (M % BM) || (N % BN) || (K % BK) || (G % 4) ||
      (K % 4)) {
    long total = (long)M * N;
    naive_kernel<<<(unsigned)((total + 255) / 256), 256, 0, stream>>>(
        x, qw, sw, bias, y, M, N, K, G);
    return;
  }

  short* xb = (short*)d_ws;
  short* wb = xb + MK;

  const int kq = K / 4;        // 4-elem runs per row
  const int gq = G / 4;        // 4-elem runs per group
  int kqshift = ((kq & (kq - 1)) == 0) ? __builtin_ctz((unsigned)kq) : -1;
  int gqshift = ((gq & (gq - 1)) == 0) ? __builtin_ctz((unsigned)gq) : -1;

  long nx4 = MK / 4;
  long total4 = nx4 + NK / 4;
  prep_kernel<<<2048, 256, 0, stream>>>(x, qw, sw, xb, wb, nx4, total4,
                                        kq, kqshift, gq, gqshift, ngroups);

  dim3 grid((unsigned)(N / BN), (unsigned)(M / BM));
  gemm_bt_kernel<<<grid, 256, 0, stream>>>(xb, wb, bias, y, M, N, K);
}